// Round 7
// baseline (445.680 us; speedup 1.0000x reference)
//
#include <hip/hip_runtime.h>
#include <hip/hip_bf16.h>
#include <stdint.h>

#define N_NODES 50000
#define N_PAD   50048   // 782 * 64
#define E_EDGES 800000
#define MT      391     // row tiles of 128 (heads kernel)

typedef __bf16 bf16x8 __attribute__((ext_vector_type(8)));
typedef __bf16 bf16x4 __attribute__((ext_vector_type(4)));
typedef float  f32x4  __attribute__((ext_vector_type(4)));

// ---------------- CSR build ----------------
__global__ void count_deg(const int* __restrict__ ei, int* __restrict__ cnt) {
    int e = blockIdx.x * blockDim.x + threadIdx.x;
    if (e < E_EDGES) atomicAdd(&cnt[ei[E_EDGES + e]], 1);
}

#define SCAN_B 1024
__global__ void scan_block(const int* __restrict__ cnt, int* __restrict__ ptr,
                           int* __restrict__ bsum, int n) {
    __shared__ int buf[SCAN_B];
    int i = blockIdx.x * SCAN_B + threadIdx.x;
    int v = (i < n) ? cnt[i] : 0;
    buf[threadIdx.x] = v;
    __syncthreads();
    #pragma unroll
    for (int off = 1; off < SCAN_B; off <<= 1) {
        int t = (threadIdx.x >= (unsigned)off) ? buf[threadIdx.x - off] : 0;
        __syncthreads();
        buf[threadIdx.x] += t;
        __syncthreads();
    }
    if (i < n) ptr[i] = buf[threadIdx.x] - v;
    if (threadIdx.x == SCAN_B - 1) bsum[blockIdx.x] = buf[SCAN_B - 1];
}

__global__ void scan_bsums(const int* __restrict__ bsum, int* __restrict__ boff,
                           int nb, int* __restrict__ total_out) {
    __shared__ int buf[SCAN_B];
    int v = ((int)threadIdx.x < nb) ? bsum[threadIdx.x] : 0;
    buf[threadIdx.x] = v;
    __syncthreads();
    #pragma unroll
    for (int off = 1; off < SCAN_B; off <<= 1) {
        int t = (threadIdx.x >= (unsigned)off) ? buf[threadIdx.x - off] : 0;
        __syncthreads();
        buf[threadIdx.x] += t;
        __syncthreads();
    }
    if ((int)threadIdx.x < nb) boff[threadIdx.x] = buf[threadIdx.x] - v;
    if (threadIdx.x == SCAN_B - 1) *total_out = buf[SCAN_B - 1];
}

__global__ void scan_add(int* __restrict__ ptr, const int* __restrict__ boff, int n) {
    int i = blockIdx.x * SCAN_B + threadIdx.x;
    if (i < n) ptr[i] += boff[blockIdx.x];
}

__global__ void fill_csr(const int* __restrict__ ei, const int* __restrict__ ptr,
                         int* __restrict__ cursor, int* __restrict__ col) {
    int e = blockIdx.x * blockDim.x + threadIdx.x;
    if (e < E_EDGES) {
        int dst = ei[E_EDGES + e];
        int pos = ptr[dst] + atomicAdd(&cursor[dst], 1);
        col[pos] = ei[e];
    }
}

// ---------------- one-shot fp32 -> bf16 conversion (x + all weights) -----------
#define XN      3200000
#define WTOT    983040
__global__ void cvt_all(const float* __restrict__ x,
                        const float* __restrict__ Ws1, const float* __restrict__ Ws2,
                        const float* __restrict__ Ws3, const float* __restrict__ Ws4,
                        const float* __restrict__ Wm1, const float* __restrict__ Wl1,
                        const float* __restrict__ Wm2, const float* __restrict__ Wl2,
                        __bf16* __restrict__ xb, __bf16* __restrict__ wbuf) {
    int i = blockIdx.x * blockDim.x + threadIdx.x;
    if (i < XN) { xb[i] = (__bf16)x[i]; return; }
    int j = i - XN;
    if (j >= WTOT) return;
    const float* s; int o;
    if      (j <  32768) { s = Ws1; o = j; }
    else if (j < 294912) { s = Ws2; o = j -  32768; }
    else if (j < 557056) { s = Ws3; o = j - 294912; }
    else if (j < 819200) { s = Ws4; o = j - 557056; }
    else if (j < 884736) { s = Wm1; o = j - 819200; }
    else if (j < 950272) { s = Wl1; o = j - 884736; }
    else if (j < 966656) { s = Wm2; o = j - 950272; }
    else                 { s = Wl2; o = j - 966656; }
    wbuf[j] = (__bf16)s[o];
}

// ---------------- aggregation 0: 64-wide rows, 8 lanes x 16B per edge ----------
__global__ __launch_bounds__(256) void agg0_gather(
    const __bf16* __restrict__ xb, const int* __restrict__ ptr,
    const int* __restrict__ col, __bf16* __restrict__ out) {
    int node = blockIdx.x * 4 + (threadIdx.x >> 6);
    int lane = threadIdx.x & 63;
    int g    = lane >> 3;          // edge slot 0..7
    int f0   = (lane & 7) << 3;    // feature chunk base
    if (node >= N_PAD) return;
    long o = (long)node * 64 + f0;
    if (node >= N_NODES) {
        if (g == 0) {
            bf16x8 z;
            #pragma unroll
            for (int i = 0; i < 8; ++i) z[i] = (__bf16)0.0f;
            *(bf16x8*)&out[o] = z;
        }
        return;
    }
    float a[8];
    #pragma unroll
    for (int i = 0; i < 8; ++i) a[i] = 0.0f;
    if (g == 0) {   // self term, added once (slot 0 only)
        bf16x8 s = *(const bf16x8*)&xb[o];
        #pragma unroll
        for (int i = 0; i < 8; ++i) a[i] = (float)s[i];
    }
    int e0 = ptr[node], e1 = ptr[node + 1];
    int e = e0;
    for (; e + 16 <= e1; e += 16) {
        int c0 = col[e + g];
        int c1 = col[e + 8 + g];
        bf16x8 v0 = *(const bf16x8*)&xb[(c0 << 6) + f0];
        bf16x8 v1 = *(const bf16x8*)&xb[(c1 << 6) + f0];
        #pragma unroll
        for (int i = 0; i < 8; ++i) a[i] += (float)v0[i] + (float)v1[i];
    }
    int rem = e1 - e;   // 0..15, wave-uniform
    if (rem > 0) {
        int u0 = (g < rem) ? g : 0;        float m0 = (g < rem) ? 1.0f : 0.0f;
        int i1 = g + 8;
        int u1 = (i1 < rem) ? i1 : 0;      float m1 = (i1 < rem) ? 1.0f : 0.0f;
        int c0 = col[e + u0];
        int c1 = col[e + u1];
        bf16x8 v0 = *(const bf16x8*)&xb[(c0 << 6) + f0];
        bf16x8 v1 = *(const bf16x8*)&xb[(c1 << 6) + f0];
        #pragma unroll
        for (int i = 0; i < 8; ++i) a[i] += m0 * (float)v0[i] + m1 * (float)v1[i];
    }
    #pragma unroll
    for (int i = 0; i < 8; ++i) {
        a[i] += __shfl_xor(a[i], 8, 64);
        a[i] += __shfl_xor(a[i], 16, 64);
        a[i] += __shfl_xor(a[i], 32, 64);
    }
    if (g == 0) {
        bf16x8 r;
        #pragma unroll
        for (int i = 0; i < 8; ++i) r[i] = (__bf16)a[i];
        *(bf16x8*)&out[o] = r;
    }
}

// ---------------- aggregation t: r1 winner (44 VGPR, occ ~42%) -----------------
__global__ __launch_bounds__(256) void aggt_gather(
    const __bf16* __restrict__ t, const int* __restrict__ ptr,
    const int* __restrict__ col, const float* __restrict__ b_m1,
    const float* __restrict__ b_l1, __bf16* __restrict__ p) {
    int node = blockIdx.x * 8 + (threadIdx.x >> 5);
    if (node >= N_NODES) return;
    int hl = threadIdx.x & 31;
    int f0 = hl << 3;
    float a[8];
    {
        bf16x8 s = *(const bf16x8*)&t[((long)node << 8) + f0];
        #pragma unroll
        for (int i = 0; i < 8; ++i) a[i] = (float)s[i];
    }
    int e0 = ptr[node], e1 = ptr[node + 1];
    int e = e0;
    for (; e + 8 <= e1; e += 8) {
        int c[8];
        #pragma unroll
        for (int u = 0; u < 8; ++u) c[u] = col[e + u];
        bf16x8 v[8];
        #pragma unroll
        for (int u = 0; u < 8; ++u) v[u] = *(const bf16x8*)&t[((long)c[u] << 8) + f0];
        #pragma unroll
        for (int u = 0; u < 8; ++u)
            #pragma unroll
            for (int i = 0; i < 8; ++i) a[i] += (float)v[u][i];
    }
    int rem = e1 - e;   // 0..7 per node
    if (rem > 0) {
        #pragma unroll
        for (int u = 0; u < 7; ++u) {
            int   uu = (u < rem) ? u : 0;
            float m  = (u < rem) ? 1.0f : 0.0f;
            int   cc = col[e + uu];
            bf16x8 v = *(const bf16x8*)&t[((long)cc << 8) + f0];
            #pragma unroll
            for (int i = 0; i < 8; ++i) a[i] += m * (float)v[i];
        }
    }
    const float* bp = (f0 < 128) ? (b_m1 + f0) : (b_l1 + (f0 - 128));
    f32x4 b0 = *(const f32x4*)bp;
    f32x4 b1 = *(const f32x4*)(bp + 4);
    bf16x8 r;
    #pragma unroll
    for (int i = 0; i < 4; ++i) r[i]     = (__bf16)fmaxf(a[i]     + b0[i], 0.0f);
    #pragma unroll
    for (int i = 0; i < 4; ++i) r[4 + i] = (__bf16)fmaxf(a[4 + i] + b1[i], 0.0f);
    *(bf16x8*)&p[((long)node << 8) + f0] = r;
}

// ---------------- async global->LDS helper -------------------------------------
__device__ __forceinline__ void gl_lds16(const __bf16* g, __bf16* l) {
    __builtin_amdgcn_global_load_lds(
        (const __attribute__((address_space(1))) uint32_t*)g,
        (__attribute__((address_space(3))) uint32_t*)l, 16, 0, 0);
}

// ================================================================================
// FUSED shared-MLP + projection, counted-vmcnt pipeline (r6-verified ledger)
// + per-block K-CHUNK PHASE ROTATION (r7): all blocks previously read identical
// chunk addresses in lockstep -> all 32 CUs of an XCD hammer the same few L2
// lines/banks simultaneously (effective 8.6 TB/s of 34.5 ceiling). K-accumulation
// is commutative, so block b processes k-chunks in order (c+phase)&15,
// phase=(blockIdx.x>>3)&15 -> the 32 CUs of one XCD spread over all 16 chunks.
// Only ADDRESSES change; barrier/vmcnt ledger is byte-identical to r6.
// ================================================================================
#define P_WAITN(n) asm volatile("s_waitcnt vmcnt(" #n ")" ::: "memory")
#define P_LGKM0 asm volatile("s_waitcnt lgkmcnt(0)" ::: "memory")
#define P_BAR   __builtin_amdgcn_s_barrier()

// stage one chunk (32 KB, 4 gl_lds16 per wave, uniform for both geometries)
__device__ __forceinline__ void stage_chunk(const __bf16* __restrict__ W, int Kdim,
                                            int k0, bool rows512,
                                            __bf16* __restrict__ buf,
                                            int wid, int lane) {
    if (rows512) {   // [512][32]: 64 B rows, granule kt of 4, slot kt^((r>>1)&3)
        int r16 = lane >> 2, sl = lane & 3;
        #pragma unroll
        for (int i = 0; i < 4; ++i) {
            int cc = wid * 4 + i;
            int r  = cc * 16 + r16;
            int kt = sl ^ ((r >> 1) & 3);
            gl_lds16(W + (long)r * Kdim + k0 + kt * 8, buf + cc * 512);
        }
    } else {         // [256][64]: 128 B rows, granule g of 8, slot g^(r&7)
        int r8 = lane >> 3, sl = lane & 7;
        #pragma unroll
        for (int i = 0; i < 4; ++i) {
            int cc = wid * 4 + i;
            int r  = cc * 8 + r8;
            int kt = sl ^ (r & 7);
            gl_lds16(W + (long)r * Kdim + k0 + kt * 8, buf + cc * 512);
        }
    }
}

// kk = ROTATED k-chunk index (selects A's k-granules); buf layout is k-relative.
__device__ __forceinline__ void chunk_mfma4(const __bf16* __restrict__ sAct,
    const __bf16* __restrict__ buf, int kk, int rA, int q, int wncol,
    f32x4 (&acc)[4][4]) {
    const int g   = kk * 4 + q;
    const int sla = ((g & 56) | ((g & 7) ^ (rA & 7))) << 3;
    bf16x8 af[4], bfr[4];
    #pragma unroll
    for (int mi = 0; mi < 4; ++mi)
        af[mi] = *(const bf16x8*)&sAct[(mi * 16 + rA) * 512 + sla];
    #pragma unroll
    for (int ni = 0; ni < 4; ++ni) {
        int wr = wncol + ni * 16 + rA;
        bfr[ni] = *(const bf16x8*)&buf[wr * 32 + ((q ^ ((wr >> 1) & 3)) << 3)];
    }
    #pragma unroll
    for (int mi = 0; mi < 4; ++mi)
        #pragma unroll
        for (int ni = 0; ni < 4; ++ni)
            acc[mi][ni] = __builtin_amdgcn_mfma_f32_16x16x32_bf16(
                af[mi], bfr[ni], acc[mi][ni], 0, 0, 0);
}

__device__ __forceinline__ void chunk_mfma_a0(const __bf16* __restrict__ act0,
    const __bf16* __restrict__ buf, int c, int rA, int q, int wncol,
    f32x4 (&acc)[4][4]) {
    const int g   = c * 4 + q;                  // 0..7
    const int sla = (g ^ (rA & 7)) << 3;
    bf16x8 af[4], bfr[4];
    #pragma unroll
    for (int mi = 0; mi < 4; ++mi)
        af[mi] = *(const bf16x8*)&act0[(mi * 16 + rA) * 64 + sla];
    #pragma unroll
    for (int ni = 0; ni < 4; ++ni) {
        int wr = wncol + ni * 16 + rA;
        bfr[ni] = *(const bf16x8*)&buf[wr * 32 + ((q ^ ((wr >> 1) & 3)) << 3)];
    }
    #pragma unroll
    for (int mi = 0; mi < 4; ++mi)
        #pragma unroll
        for (int ni = 0; ni < 4; ++ni)
            acc[mi][ni] = __builtin_amdgcn_mfma_f32_16x16x32_bf16(
                af[mi], bfr[ni], acc[mi][ni], 0, 0, 0);
}

// proj chunk: K=64, W buf [256][64], two sub-k of 8 MFMAs. kp = rotated index.
__device__ __forceinline__ void chunk_mfma_proj(const __bf16* __restrict__ sAct,
    const __bf16* __restrict__ buf, int kp, int rA, int q, int wnp,
    f32x4 (&accp)[4][2]) {
    #pragma unroll
    for (int s = 0; s < 2; ++s) {
        const int g   = kp * 8 + s * 4 + q;
        const int sla = ((g & 56) | ((g & 7) ^ (rA & 7))) << 3;
        bf16x8 af[4], bfr[2];
        #pragma unroll
        for (int mi = 0; mi < 4; ++mi)
            af[mi] = *(const bf16x8*)&sAct[(mi * 16 + rA) * 512 + sla];
        #pragma unroll
        for (int ni = 0; ni < 2; ++ni) {
            int wr = wnp + ni * 16 + rA;
            int gB = s * 4 + q;
            bfr[ni] = *(const bf16x8*)&buf[wr * 64 + ((gB ^ (wr & 7)) << 3)];
        }
        #pragma unroll
        for (int mi = 0; mi < 4; ++mi)
            #pragma unroll
            for (int ni = 0; ni < 2; ++ni)
                accp[mi][ni] = __builtin_amdgcn_mfma_f32_16x16x32_bf16(
                    af[mi], bfr[ni], accp[mi][ni], 0, 0, 0);
    }
}

template <int ACTn>   // 1 = lrelu(0.1), 2 = relu
__device__ __forceinline__ void writeback_act(__bf16* __restrict__ sAct,
    f32x4 (&acc)[4][4], const float* __restrict__ bv,
    int wn, int ccol, int crow) {
    #pragma unroll
    for (int mi = 0; mi < 4; ++mi)
        #pragma unroll
        for (int ni = 0; ni < 4; ++ni) {
            int cc = wn + ni * 16 + ccol;
            int g  = cc >> 3;
            #pragma unroll
            for (int p = 0; p < 4; ++p) {
                int rr = mi * 16 + crow + p;
                float v = acc[mi][ni][p] + bv[ni];
                if (ACTn == 1) v = (v > 0.0f) ? v : 0.1f * v;
                else           v = fmaxf(v, 0.0f);
                int sl = (g & 56) | ((g & 7) ^ (rr & 7));
                sAct[rr * 512 + sl * 8 + (cc & 7)] = (__bf16)v;
            }
        }
}

// one 512-wide layer under the counted pipeline, with phase rotation.
// Position c consumes k-chunk (c+phase)&15; stage for position p sources
// k-chunk (p+phase)&15 -> bijective, every W chunk staged exactly once.
// Next-layer positions 0/1 staged at c=14/15 with caller-provided k0n_c0/c1.
template <int ACTn>
__device__ __forceinline__ void layer512_pipe(
    __bf16* __restrict__ sAct, __bf16* __restrict__ s0, __bf16* __restrict__ s1,
    const __bf16* __restrict__ W,
    const __bf16* __restrict__ Wn, int Kn, bool n512, int k0n_c0, int k0n_c1,
    int phase, const float* __restrict__ bv,
    int wn, int rA, int q, int ccol, int crow, int wid, int lane) {
    f32x4 acc[4][4];
    #pragma unroll
    for (int i = 0; i < 4; ++i)
        #pragma unroll
        for (int j = 0; j < 4; ++j) acc[i][j] = (f32x4)0.0f;
    #pragma unroll
    for (int c = 0; c < 16; ++c) {
        __bf16* cur = (c & 1) ? s1 : s0;
        int kk = (c + phase) & 15;
        P_WAITN(4); P_BAR;
        chunk_mfma4(sAct, cur, kk, rA, q, wn, acc);
        if (c < 15) {
            P_LGKM0; P_BAR;
            if (c <= 13) stage_chunk(W, 512, ((c + 2 + phase) & 15) * 32, true, cur, wid, lane);
            else         stage_chunk(Wn, Kn, k0n_c0, n512, s0, wid, lane);    // next c0
        } else {
            P_LGKM0; P_BAR;                       // all reads of sAct retired
            writeback_act<ACTn>(sAct, acc, bv, wn, ccol, crow);
            __syncthreads();                      // writes visible (drains vm too)
            stage_chunk(Wn, Kn, k0n_c1, n512, s1, wid, lane);                 // next c1
        }
    }
}

__global__ __launch_bounds__(512) void mlp_fused(
    const __bf16* __restrict__ a0,   // agg0b [N_PAD][64]
    const __bf16* __restrict__ w1, const float* __restrict__ b1,
    const __bf16* __restrict__ w2, const float* __restrict__ b2,
    const __bf16* __restrict__ w3, const float* __restrict__ b3,
    const __bf16* __restrict__ w4, const float* __restrict__ b4,
    const __bf16* __restrict__ wp,   // wml [256][512]
    __bf16* __restrict__ tg)         // t [N_PAD][256]
{
    __shared__ __bf16 lds[69632];    // 136 KB
    __bf16* act0 = lds;              // [64][64]
    __bf16* sAct = lds + 4096;       // [64][512]
    __bf16* s0   = lds + 36864;      // ring slot 0 (32 KB)
    __bf16* s1   = lds + 53248;      // ring slot 1 (32 KB)

    const int tid  = threadIdx.x;
    const int wid  = tid >> 6;
    const int lane = tid & 63;
    const long blockRow = (long)blockIdx.x * 64;
    const int phase  = (blockIdx.x >> 3) & 15;   // 512-layer rotation
    const int phasep = (blockIdx.x >> 3) & 7;    // proj rotation (8 chunks)

    const int rA   = lane & 15;
    const int q    = lane >> 4;
    const int ccol = lane & 15;
    const int crow = (lane >> 4) << 2;
    const int wn   = wid << 6;       // 512-wide layers
    const int wnp  = wid << 5;       // proj (256-wide)

    // bias preload (keeps VMEM out of the counted pipeline; drained by the
    // first WAITN since they are the oldest outstanding loads)
    float bv1[4], bv2[4], bv3[4], bv4[4];
    #pragma unroll
    for (int ni = 0; ni < 4; ++ni) {
        int idx = wn + ni * 16 + ccol;
        bv1[ni] = b1[idx]; bv2[ni] = b2[idx]; bv3[ni] = b3[idx]; bv4[ni] = b4[idx];
    }

    // prime: act0 (1 gl/wave) + chunk0 (L1 k0..31) + chunk1 (L1 k32..63)
    // (L1 is 2 chunks only — not rotated; startup transient)
    {
        int srow = lane >> 3;
        int skg  = (lane & 7) ^ srow;
        gl_lds16(a0 + (blockRow + wid * 8 + srow) * 64 + skg * 8, act0 + wid * 512);
    }
    stage_chunk(w1, 64, 0,  true, s0, wid, lane);
    stage_chunk(w1, 64, 32, true, s1, wid, lane);

    // ---- L1: 64 -> 512 (A = act0) ----
    {
        f32x4 acc[4][4];
        #pragma unroll
        for (int i = 0; i < 4; ++i)
            #pragma unroll
            for (int j = 0; j < 4; ++j) acc[i][j] = (f32x4)0.0f;
        // j=0: outstanding bias+act0(1)+c0(4)+c1(4); vmcnt(4) -> act0+c0 landed
        P_WAITN(4); P_BAR;
        chunk_mfma_a0(act0, s0, 0, rA, q, wn, acc);
        P_LGKM0; P_BAR;
        stage_chunk(w2, 512, (phase & 15) * 32, true, s0, wid, lane);       // L2 c0
        // j=1: outstanding c1(4)+w2c0(4)=8; vmcnt(4) -> c1 landed
        P_WAITN(4); P_BAR;
        chunk_mfma_a0(act0, s1, 1, rA, q, wn, acc);
        writeback_act<1>(sAct, acc, bv1, wn, ccol, crow); // sAct has no readers yet
        __syncthreads();
        stage_chunk(w2, 512, ((1 + phase) & 15) * 32, true, s1, wid, lane); // L2 c1
    }

    // ---- L2, L3 (lrelu), L4 (+b4 then relu) ----
    layer512_pipe<1>(sAct, s0, s1, w2, w3, 512, true,
                     (phase & 15) * 32, ((1 + phase) & 15) * 32, phase,
                     bv2, wn, rA, q, ccol, crow, wid, lane);
    layer512_pipe<1>(sAct, s0, s1, w3, w4, 512, true,
                     (phase & 15) * 32, ((1 + phase) & 15) * 32, phase,
                     bv3, wn, rA, q, ccol, crow, wid, lane);
    layer512_pipe<2>(sAct, s0, s1, w4, wp, 512, false,
                     (phasep & 7) * 64, ((1 + phasep) & 7) * 64, phase,
                     bv4, wn, rA, q, ccol, crow, wid, lane);

    // ---- proj: 512 -> 256 (8 chunks of K=64), no bias/act, rotated ----
    {
        f32x4 accp[4][2];
        #pragma unroll
        for (int i = 0; i < 4; ++i)
            #pragma unroll
            for (int j = 0; j < 2; ++j) accp[i][j] = (f32x4)0.0f;
        #pragma unroll
        for (int c = 0; c < 8; ++c) {
            __bf16* cur = (c & 1) ? s1 : s0;
            int kp = (c + phasep) & 7;
            // ledger: c<=6 have 8 in flight -> vmcnt(4) waits chunk c;
            // c==7 has only chunk 7's own 4 in flight -> must drain fully.
            if (c == 7) { P_WAITN(0); } else { P_WAITN(4); }
            P_BAR;
            chunk_mfma_proj(sAct, cur, kp, rA, q, wnp, accp);
            P_LGKM0; P_BAR;
            if (c < 6) stage_chunk(wp, 512, ((c + 2 + phasep) & 7) * 64, false, cur, wid, lane);
        }
        // stage 64x256 bf16 t-tile into s0 (all s0/s1 reads retired at the c=7
        // trailing barrier), then coalesced 16B stores.
        #pragma unroll
        for (int mi = 0; mi < 4; ++mi)
            #pragma unroll
            for (int ni = 0; ni < 2; ++ni)
                #pragma unroll
                for (int p = 0; p < 4; ++p)
                    s0[(mi * 16 + crow + p) * 256 + wnp + ni * 16 + ccol] =
                        (__bf16)accp[mi][ni][p];
        __syncthreads();
        int rr = tid >> 3;
        int c0 = (tid & 7) << 5;
        const bf16x8* s = (const bf16x8*)&s0[rr * 256 + c0];
        __bf16* d = tg + (blockRow + rr) * 256 + c0;
        #pragma unroll
        for (int i = 0; i < 4; ++i) *(bf16x8*)(d + i * 8) = s[i];
    }
}

// ---------------- 128x128 MFMA GEMM core (heads only now) ----------------------
template <int NCOL>
__device__ __forceinline__ void swizzle_xy(int bid, int& x, int& y) {
    int grp  = bid / (8 * NCOL);
    int rem  = bid - grp * (8 * NCOL);
    int base = grp * 8;
    int width = MT - base; if (width > 8) width = 8;
    x = base + rem % width;
    y = rem / width;
}

template <int ACT, bool BIAS, bool OUT_BF16, bool MCHK>
__device__ __forceinline__ void gemm_core(
    const __bf16* __restrict__ A, int lda, const __bf16* __restrict__ W,
    const float* __restrict__ bias, void* __restrict__ Cout, int ldc,
    int K, long Mstore, long blockRow, int blockCol,
    __bf16* __restrict__ smem) {
    __bf16* As = smem;
    __bf16* Ws = smem + 8192;
    const int tid  = threadIdx.x;
    const int wid  = tid >> 6;
    const int lane = tid & 63;
    const int wm = (wid >> 1) << 6;
    const int wn = (wid & 1) << 6;

    f32x4 acc[4][4];
    #pragma unroll
    for (int i = 0; i < 4; ++i)
        #pragma unroll
        for (int j = 0; j < 4; ++j) acc[i][j] = (f32x4)0.0f;

    const int srow = lane >> 3;
    const int skg  = (lane & 7) ^ srow;
    const __bf16* gA[4]; const __bf16* gW[4];
    __bf16 *lA[4], *lW[4];
    #pragma unroll
    for (int i = 0; i < 4; ++i) {
        int c = wid * 4 + i;
        gA[i] = A + (blockRow + c * 8 + srow) * (long)lda + skg * 8;
        gW[i] = W + ((long)blockCol + c * 8 + srow) * (long)K + skg * 8;
        lA[i] = As + c * 512;
        lW[i] = Ws + c * 512;
    }

    const int rA = lane & 15;
    const int q  = lane >> 4;
    const int r7 = rA & 7;

    for (int k0 = 0; k0 < K; k0 += 64) {
        #pragma unroll
        for (int i = 0; i < 4; ++i) gl_lds16(gA[i] + k0, lA[i]);
        #pragma unroll
        for (int i = 0; i < 4; ++i) gl_lds16(gW[i] + k0, lW[i]);
        __syncthreads();

        #pragma unroll
        for (int s = 0; s < 2; ++s) {
            const int slot = ((s * 4 + q) ^ r7) * 8;
            bf16x8 af[4], bf[4];
            #pragma unroll
            for (int mi = 0; mi < 4; ++mi)
                af[mi] = *(const bf16x8*)&As[(wm + mi * 16 + rA) * 64 + slot];
            #pragma unroll
            for (int ni = 0; ni < 4; ++ni)
                bf[ni] = *(const bf16x8*)&Ws[(wn + ni * 16 + rA) * 64 + slot];
            #pragma unroll
            for (int mi = 0; mi < 4; ++mi)
                #pragma unroll
                for (int ni = 0; ni < 4; ++ni)
                    acc[mi][ni] = __builtin_amdgcn_mfma_f32_16x16x32_bf16(
                        af[mi], bf[ni], acc[mi][ni], 0, 0, 0);
        }
        __syncthreads();
    }

    const int ccol = lane & 15;
    const int crow = (lane >> 4) << 2;
    if (OUT_BF16 && !MCHK) {
        #pragma unroll
        for (int mi = 0; mi < 4; ++mi) {
            #pragma unroll
            for (int ni = 0; ni < 4; ++ni) {
                int gc = wn + ni * 16 + ccol;
                float bv = BIAS ? bias[blockCol + gc] : 0.0f;
                #pragma unroll
                for (int r = 0; r < 4; ++r) {
                    float v = acc[mi][ni][r] + bv;
                    if (ACT == 1) v = (v > 0.0f) ? v : 0.1f * v;
                    else if (ACT == 2) v = fmaxf(v, 0.0f);
                    smem[(wm + mi * 16 + crow + r) * 128 + gc] = (__bf16)v;
                }
            }
        }
        __syncthreads();
        #pragma unroll
        for (int i = 0; i < 8; ++i) {
            int o   = (i * 256 + tid) * 8;
            int row = o >> 7;
            int co  = o & 127;
            *(bf16x8*)((__bf16*)Cout + (blockRow + row) * (long)ldc + blockCol + co) =
                *(const bf16x8*)&smem[o];
        }
    } else if (!OUT_BF16) {
        // fp32 staged path (ldc == 128): two 64-row halves in the dead 32 KB LDS,
        // coalesced f32x4 stores, row-guarded.
        float* fsmem = (float*)smem;
        #pragma unroll
        for (int half = 0; half < 2; ++half) {
            __syncthreads();
            if ((wm >> 6) == half) {
                #pragma unroll
                for (int mi = 0; mi < 4; ++mi) {
                    #pragma unroll
                    for (int ni = 0; ni < 4; ++ni) {
                        int gc = wn + ni * 16 + ccol;
                        float bv = BIAS ? bias[blockCol + gc] : 0.0f;
                        #pragma unroll
                        for (int r = 0; r < 4; ++r) {
                            float v = acc[mi][ni][r] + bv;
                            if (ACT == 1) v = (v > 0.0f) ? v : 0.1f * v;
                            else if (ACT == 2) v = fmaxf(v, 0.0f);
                            fsmem[(mi * 16 + crow + r) * 128 + gc] = v;
                        }
                    }
                }
            }
            __syncthreads();
            #pragma unroll
            for (int i = 0; i < 8; ++i) {
                int o   = i * 256 + tid;
                int row = o >> 5;
                int co  = (o & 31) * 4;
                long gr = blockRow + half * 64 + row;
                if (!MCHK || gr < Mstore)
                    *(f32x4*)((float*)Cout + gr * (long)ldc + blockCol + co) =
                        *(const f32x4*)&fsmem[o * 4];
            }
        }
    } else {
        #pragma unroll
        for (int mi = 0; mi < 4; ++mi) {
            #pragma unroll
            for (int ni = 0; ni < 4; ++ni) {
                long gr0 = blockRow + wm + mi * 16 + crow;
                int  gc  = blockCol + wn + ni * 16 + ccol;
                float bv = BIAS ? bias[gc] : 0.0f;
                #pragma unroll
                for (int r = 0; r < 4; ++r) {
                    long gr = gr0 + r;
                    if (!MCHK || gr < Mstore) {
                        float v = acc[mi][ni][r] + bv;
                        if (ACT == 1) v = (v > 0.0f) ? v : 0.1f * v;
                        else if (ACT == 2) v = fmaxf(v, 0.0f);
                        ((__bf16*)Cout)[gr * ldc + gc] = (__bf16)v;
                    }
                }
            }
        }
    }
}

// both heads in one 1D dispatch; K=128 (each head uses its half of p), lda=256.
__global__ __launch_bounds__(256) void gemm_heads(
    const __bf16* __restrict__ p, const __bf16* __restrict__ wm2,
    const float* __restrict__ b_m2, float* __restrict__ mu,
    const __bf16* __restrict__ wl2, const float* __restrict__ b_l2,
    float* __restrict__ lv) {
    __shared__ __bf16 smem[128 * 128];
    int x, hd;
    swizzle_xy<2>(blockIdx.x, x, hd);
    if (hd == 0)
        gemm_core<0, true, false, true>(p, 256, wm2, b_m2, mu, 128, 128, N_NODES,
                                        (long)x * 128, 0, smem);
    else
        gemm_core<0, true, false, true>(p + 128, 256, wl2, b_l2, lv, 128, 128, N_NODES,
                                        (long)x * 128, 0, smem);
}

extern "C" void kernel_launch(void* const* d_in, const int* in_sizes, int n_in,
                              void* d_out, int out_size, void* d_ws, size_t ws_size,
                              hipStream_t stream) {
    const float* x    = (const float*)d_in[0];
    const int*   ei   = (const int*)d_in[1];
    const float* W_s1 = (const float*)d_in[2];
    const float* b_s1 = (const float*)d_in[3];
    const float* W_s2 = (const float*)d_in[4];
    const float* b_s2 = (const float*)d_in[5];
    const float* W_s3 = (const float*)d_in[6];
    const float* b_s3 = (const float*)d_in[7];
    const float* W_s4 = (const float*)d_in[8];
    const float* b_s4 = (const float*)d_in[9];
    const float* W_m1 = (const float*)d_in[10];
    const float* b_m1 = (const float*)d_in[11];
    const float* W_m2 = (const float*)d_in[12];
    const float* b_m2 = (const float*)d_in[13];
    const float* W_l1 = (const float*)d_in[14];
    const float* b_l1 = (const float*)d_in[15];
    const float* W_l2 = (const float*)d_in[16];
    const float* b_l2 = (const float*)d_in[17];

    char* ws = (char*)d_ws;
    size_t off = 0;
    auto carve = [&](size_t bytes) -> void* {
        void* p = ws + off;
        off = (off + bytes + 255) & ~(size_t)255;
        return p;
    };
    int* ptr  = (int*)carve((size_t)(N_NODES + 1) * 4);
    int* col  = (int*)carve((size_t)E_EDGES * 4);
    int* bsum = (int*)carve(SCAN_B * 4);
    int* boff = (int*)carve(SCAN_B * 4);
    __bf16* wbuf = (__bf16*)carve((size_t)WTOT * 2);
    __bf16* w1  = wbuf;
    __bf16* w2  = wbuf +  32768;
    __bf16* w3  = wbuf + 294912;
    __bf16* w4  = wbuf + 557056;
    __bf16* wml = wbuf + 819200;   // [W_m1 ; W_l1] rows, 256x512
    __bf16* wm2 = wbuf + 950272;
    __bf16* wl2 = wbuf + 966656;
    __bf16* xb    = (__bf16*)carve((size_t)XN * 2);
    __bf16* agg0b = (__bf16*)carve((size_t)N_PAD * 64 * 2);
    __bf16* B1    = (__bf16*)carve((size_t)N_PAD * 512 * 2);
    __bf16* B2    = (__bf16*)carve((size_t)N_PAD * 512 * 2);

    // count/cursor arrays alias B1/B2 — first real writes happen after CSR build
    // completes (stream-ordered).
    int* cnt = (int*)B1;
    int* cur = (int*)B2;

    (void)hipMemsetAsync(cnt, 0, (size_t)N_NODES * 4, stream);
    (void)hipMemsetAsync(cur, 0, (size_t)N_NODES * 4, stream);

    // CSR build
    const int NB = (N_NODES + SCAN_B - 1) / SCAN_B;  // 49
    count_deg<<<E_EDGES / 256, 256, 0, stream>>>(ei, cnt);
    scan_block<<<NB, SCAN_B, 0, stream>>>(cnt, ptr, bsum, N_NODES);
    scan_bsums<<<1, SCAN_B, 0, stream>>>(bsum, boff, NB, &ptr[N_NODES]);
    scan_add<<<NB, SCAN_B, 0, stream>>>(ptr, boff, N_NODES);
    fill_csr<<<E_EDGES / 256, 256, 0, stream>>>(ei, ptr, cur, col);

    // one-shot conversions
    cvt_all<<<(XN + WTOT + 255) / 256, 256, 0, stream>>>(
        x, W_s1, W_s2, W_s3, W_s4, W_m1, W_l1, W_m2, W_l2, xb, wbuf);

    // first aggregation
    agg0_gather<<<N_PAD / 4, 256, 0, stream>>>(xb, ptr, col, agg0b);

    // fused shared-MLP + projection: agg0b -> t (N_PAD x 256 bf16)
    __bf16* t = B1;
    mlp_fused<<<N_PAD / 64, 512, 0, stream>>>(agg0b, w1, b_s1, w2, b_s2,
                                              w3, b_s3, w4, b_s4, wml, t);

    // second aggregation, fused bias+relu
    __bf16* p = B2;  // N x 256 bf16
    aggt_gather<<<(N_NODES + 7) / 8, 256, 0, stream>>>(t, ptr, col, b_m1, b_l1, p);

    // heads (one swizzled 1D dispatch)
    float* mu = (float*)d_out;
    float* lv = mu + (size_t)N_NODES * 128;
    gemm_heads<<<MT * 2, 256, 0, stream>>>(p, wm2, b_m2, mu, wl2, b_l2, lv);
}

// Round 8
// 443.421 us; speedup vs baseline: 1.0051x; 1.0051x over previous
//
#include <hip/hip_runtime.h>
#include <hip/hip_bf16.h>
#include <stdint.h>

#define N_NODES 50000
#define N_PAD   50048   // 782 * 64
#define E_EDGES 800000
#define MT      391     // row tiles of 128 (heads kernel)

typedef __bf16 bf16x8 __attribute__((ext_vector_type(8)));
typedef __bf16 bf16x4 __attribute__((ext_vector_type(4)));
typedef float  f32x4  __attribute__((ext_vector_type(4)));

// ---------------- CSR build ----------------
__global__ void count_deg(const int* __restrict__ ei, int* __restrict__ cnt) {
    int e = blockIdx.x * blockDim.x + threadIdx.x;
    if (e < E_EDGES) atomicAdd(&cnt[ei[E_EDGES + e]], 1);
}

#define SCAN_B 1024
__global__ void scan_block(const int* __restrict__ cnt, int* __restrict__ ptr,
                           int* __restrict__ bsum, int n) {
    __shared__ int buf[SCAN_B];
    int i = blockIdx.x * SCAN_B + threadIdx.x;
    int v = (i < n) ? cnt[i] : 0;
    buf[threadIdx.x] = v;
    __syncthreads();
    #pragma unroll
    for (int off = 1; off < SCAN_B; off <<= 1) {
        int t = (threadIdx.x >= (unsigned)off) ? buf[threadIdx.x - off] : 0;
        __syncthreads();
        buf[threadIdx.x] += t;
        __syncthreads();
    }
    if (i < n) ptr[i] = buf[threadIdx.x] - v;
    if (threadIdx.x == SCAN_B - 1) bsum[blockIdx.x] = buf[SCAN_B - 1];
}

__global__ void scan_bsums(const int* __restrict__ bsum, int* __restrict__ boff,
                           int nb, int* __restrict__ total_out) {
    __shared__ int buf[SCAN_B];
    int v = ((int)threadIdx.x < nb) ? bsum[threadIdx.x] : 0;
    buf[threadIdx.x] = v;
    __syncthreads();
    #pragma unroll
    for (int off = 1; off < SCAN_B; off <<= 1) {
        int t = (threadIdx.x >= (unsigned)off) ? buf[threadIdx.x - off] : 0;
        __syncthreads();
        buf[threadIdx.x] += t;
        __syncthreads();
    }
    if ((int)threadIdx.x < nb) boff[threadIdx.x] = buf[threadIdx.x] - v;
    if (threadIdx.x == SCAN_B - 1) *total_out = buf[SCAN_B - 1];
}

__global__ void scan_add(int* __restrict__ ptr, const int* __restrict__ boff, int n) {
    int i = blockIdx.x * SCAN_B + threadIdx.x;
    if (i < n) ptr[i] += boff[blockIdx.x];
}

__global__ void fill_csr(const int* __restrict__ ei, const int* __restrict__ ptr,
                         int* __restrict__ cursor, int* __restrict__ col) {
    int e = blockIdx.x * blockDim.x + threadIdx.x;
    if (e < E_EDGES) {
        int dst = ei[E_EDGES + e];
        int pos = ptr[dst] + atomicAdd(&cursor[dst], 1);
        col[pos] = ei[e];
    }
}

// ---------------- one-shot fp32 -> bf16 conversion (x + all weights) -----------
#define XN      3200000
#define WTOT    983040
__global__ void cvt_all(const float* __restrict__ x,
                        const float* __restrict__ Ws1, const float* __restrict__ Ws2,
                        const float* __restrict__ Ws3, const float* __restrict__ Ws4,
                        const float* __restrict__ Wm1, const float* __restrict__ Wl1,
                        const float* __restrict__ Wm2, const float* __restrict__ Wl2,
                        __bf16* __restrict__ xb, __bf16* __restrict__ wbuf) {
    int i = blockIdx.x * blockDim.x + threadIdx.x;
    if (i < XN) { xb[i] = (__bf16)x[i]; return; }
    int j = i - XN;
    if (j >= WTOT) return;
    const float* s; int o;
    if      (j <  32768) { s = Ws1; o = j; }
    else if (j < 294912) { s = Ws2; o = j -  32768; }
    else if (j < 557056) { s = Ws3; o = j - 294912; }
    else if (j < 819200) { s = Ws4; o = j - 557056; }
    else if (j < 884736) { s = Wm1; o = j - 819200; }
    else if (j < 950272) { s = Wl1; o = j - 884736; }
    else if (j < 966656) { s = Wm2; o = j - 950272; }
    else                 { s = Wl2; o = j - 966656; }
    wbuf[j] = (__bf16)s[o];
}

// ---------------- aggregation 0: 64-wide rows, 8 lanes x 16B per edge ----------
__global__ __launch_bounds__(256) void agg0_gather(
    const __bf16* __restrict__ xb, const int* __restrict__ ptr,
    const int* __restrict__ col, __bf16* __restrict__ out) {
    int node = blockIdx.x * 4 + (threadIdx.x >> 6);
    int lane = threadIdx.x & 63;
    int g    = lane >> 3;          // edge slot 0..7
    int f0   = (lane & 7) << 3;    // feature chunk base
    if (node >= N_PAD) return;
    long o = (long)node * 64 + f0;
    if (node >= N_NODES) {
        if (g == 0) {
            bf16x8 z;
            #pragma unroll
            for (int i = 0; i < 8; ++i) z[i] = (__bf16)0.0f;
            *(bf16x8*)&out[o] = z;
        }
        return;
    }
    float a[8];
    #pragma unroll
    for (int i = 0; i < 8; ++i) a[i] = 0.0f;
    if (g == 0) {   // self term, added once (slot 0 only)
        bf16x8 s = *(const bf16x8*)&xb[o];
        #pragma unroll
        for (int i = 0; i < 8; ++i) a[i] = (float)s[i];
    }
    int e0 = ptr[node], e1 = ptr[node + 1];
    int e = e0;
    for (; e + 16 <= e1; e += 16) {
        int c0 = col[e + g];
        int c1 = col[e + 8 + g];
        bf16x8 v0 = *(const bf16x8*)&xb[(c0 << 6) + f0];
        bf16x8 v1 = *(const bf16x8*)&xb[(c1 << 6) + f0];
        #pragma unroll
        for (int i = 0; i < 8; ++i) a[i] += (float)v0[i] + (float)v1[i];
    }
    int rem = e1 - e;   // 0..15, wave-uniform
    if (rem > 0) {
        int u0 = (g < rem) ? g : 0;        float m0 = (g < rem) ? 1.0f : 0.0f;
        int i1 = g + 8;
        int u1 = (i1 < rem) ? i1 : 0;      float m1 = (i1 < rem) ? 1.0f : 0.0f;
        int c0 = col[e + u0];
        int c1 = col[e + u1];
        bf16x8 v0 = *(const bf16x8*)&xb[(c0 << 6) + f0];
        bf16x8 v1 = *(const bf16x8*)&xb[(c1 << 6) + f0];
        #pragma unroll
        for (int i = 0; i < 8; ++i) a[i] += m0 * (float)v0[i] + m1 * (float)v1[i];
    }
    #pragma unroll
    for (int i = 0; i < 8; ++i) {
        a[i] += __shfl_xor(a[i], 8, 64);
        a[i] += __shfl_xor(a[i], 16, 64);
        a[i] += __shfl_xor(a[i], 32, 64);
    }
    if (g == 0) {
        bf16x8 r;
        #pragma unroll
        for (int i = 0; i < 8; ++i) r[i] = (__bf16)a[i];
        *(bf16x8*)&out[o] = r;
    }
}

// ---------------- aggregation t: r1 winner (44 VGPR, occ ~42%) -----------------
__global__ __launch_bounds__(256) void aggt_gather(
    const __bf16* __restrict__ t, const int* __restrict__ ptr,
    const int* __restrict__ col, const float* __restrict__ b_m1,
    const float* __restrict__ b_l1, __bf16* __restrict__ p) {
    int node = blockIdx.x * 8 + (threadIdx.x >> 5);
    if (node >= N_NODES) return;
    int hl = threadIdx.x & 31;
    int f0 = hl << 3;
    float a[8];
    {
        bf16x8 s = *(const bf16x8*)&t[((long)node << 8) + f0];
        #pragma unroll
        for (int i = 0; i < 8; ++i) a[i] = (float)s[i];
    }
    int e0 = ptr[node], e1 = ptr[node + 1];
    int e = e0;
    for (; e + 8 <= e1; e += 8) {
        int c[8];
        #pragma unroll
        for (int u = 0; u < 8; ++u) c[u] = col[e + u];
        bf16x8 v[8];
        #pragma unroll
        for (int u = 0; u < 8; ++u) v[u] = *(const bf16x8*)&t[((long)c[u] << 8) + f0];
        #pragma unroll
        for (int u = 0; u < 8; ++u)
            #pragma unroll
            for (int i = 0; i < 8; ++i) a[i] += (float)v[u][i];
    }
    int rem = e1 - e;   // 0..7 per node
    if (rem > 0) {
        #pragma unroll
        for (int u = 0; u < 7; ++u) {
            int   uu = (u < rem) ? u : 0;
            float m  = (u < rem) ? 1.0f : 0.0f;
            int   cc = col[e + uu];
            bf16x8 v = *(const bf16x8*)&t[((long)cc << 8) + f0];
            #pragma unroll
            for (int i = 0; i < 8; ++i) a[i] += m * (float)v[i];
        }
    }
    const float* bp = (f0 < 128) ? (b_m1 + f0) : (b_l1 + (f0 - 128));
    f32x4 b0 = *(const f32x4*)bp;
    f32x4 b1 = *(const f32x4*)(bp + 4);
    bf16x8 r;
    #pragma unroll
    for (int i = 0; i < 4; ++i) r[i]     = (__bf16)fmaxf(a[i]     + b0[i], 0.0f);
    #pragma unroll
    for (int i = 0; i < 4; ++i) r[4 + i] = (__bf16)fmaxf(a[4 + i] + b1[i], 0.0f);
    *(bf16x8*)&p[((long)node << 8) + f0] = r;
}

// ---------------- async global->LDS helper -------------------------------------
__device__ __forceinline__ void gl_lds16(const __bf16* g, __bf16* l) {
    __builtin_amdgcn_global_load_lds(
        (const __attribute__((address_space(1))) uint32_t*)g,
        (__attribute__((address_space(3))) uint32_t*)l, 16, 0, 0);
}

// ================================================================================
// FUSED shared-MLP + projection — 3-SLOT RING, 1 barrier/chunk (r8).
// r6's 2-slot ring forced {MFMA; lgkm0; BAR; stage} (stage overwrites the slot
// just read). With 3 slots, chunk g's slot = g%3, and the slot for chunk g+2 was
// last read at position g-1 — the single top barrier of position g already
// proves those reads retired, so stage(g+2) issues right after it, overlapping
// MFMA(g). No lgkmcnt(0), no 2nd barrier, stages ride across layer boundaries.
//
// Outstanding-load LEDGER (4 loads/wave/chunk; global chunk index g = 0..57):
//   prime: bias(16) + act0(1) + stage g0(4) + g1(4)
//   g=0:  WAIT vmcnt(0)  (drain prime; compiler may interleave bias/stage issue
//         order, so a counted wait is not provably safe here; one-time cost)
//   g=1:  vmcnt(4) no-op (already drained) — then stage g3 -> 8 in flight
//   g>=2: outstanding = {g(4), g+1(4)} = 8 -> vmcnt(4) waits chunk g.  [uniform]
//   g=56: stages nothing (g58 doesn't exist); outstanding 8 -> vmcnt(4) ok
//   g=57: outstanding = own 4 only -> MUST vmcnt(0)  (r5 bug class, pre-audited)
//   layer boundary: {BAR; writeback(ds); lgkm0; BAR} — NO vm drain.
// Slot map: chunk g -> slot g%3. Layer bases: L1 g0 (B3=0), L2 g2 (B3=2),
// L3 g18 (B3=0), L4 g34 (B3=1), proj g50 (B3=2). All mod-3 consistent.
// LDS: sAct [64][512] 64 KB (first 8 KB doubles as act0, dead after L1)
//      + 3 x 32 KB slots = 160 KB exactly (1 block/CU; AITER precedent @160 KB).
// ================================================================================
#define P_WAITN(n) asm volatile("s_waitcnt vmcnt(" #n ")" ::: "memory")
#define P_WAIT0    asm volatile("s_waitcnt vmcnt(0)" ::: "memory")
#define P_LGKM0    asm volatile("s_waitcnt lgkmcnt(0)" ::: "memory")
#define P_BAR      __builtin_amdgcn_s_barrier()
#define SLOT_ELEMS 16384

// stage one chunk (32 KB, 4 gl_lds16 per wave, uniform for both geometries)
__device__ __forceinline__ void stage_chunk(const __bf16* __restrict__ W, int Kdim,
                                            int k0, bool rows512,
                                            __bf16* __restrict__ buf,
                                            int wid, int lane) {
    if (rows512) {   // [512][32]: 64 B rows, granule kt of 4, slot kt^((r>>1)&3)
        int r16 = lane >> 2, sl = lane & 3;
        #pragma unroll
        for (int i = 0; i < 4; ++i) {
            int cc = wid * 4 + i;
            int r  = cc * 16 + r16;
            int kt = sl ^ ((r >> 1) & 3);
            gl_lds16(W + (long)r * Kdim + k0 + kt * 8, buf + cc * 512);
        }
    } else {         // [256][64]: 128 B rows, granule g of 8, slot g^(r&7)
        int r8 = lane >> 3, sl = lane & 7;
        #pragma unroll
        for (int i = 0; i < 4; ++i) {
            int cc = wid * 4 + i;
            int r  = cc * 8 + r8;
            int kt = sl ^ (r & 7);
            gl_lds16(W + (long)r * Kdim + k0 + kt * 8, buf + cc * 512);
        }
    }
}

__device__ __forceinline__ void chunk_mfma4(const __bf16* __restrict__ sAct,
    const __bf16* __restrict__ buf, int c, int rA, int q, int wncol,
    f32x4 (&acc)[4][4]) {
    const int g   = c * 4 + q;
    const int sla = ((g & 56) | ((g & 7) ^ (rA & 7))) << 3;
    bf16x8 af[4], bfr[4];
    #pragma unroll
    for (int mi = 0; mi < 4; ++mi)
        af[mi] = *(const bf16x8*)&sAct[(mi * 16 + rA) * 512 + sla];
    #pragma unroll
    for (int ni = 0; ni < 4; ++ni) {
        int wr = wncol + ni * 16 + rA;
        bfr[ni] = *(const bf16x8*)&buf[wr * 32 + ((q ^ ((wr >> 1) & 3)) << 3)];
    }
    __builtin_amdgcn_s_setprio(1);
    #pragma unroll
    for (int mi = 0; mi < 4; ++mi)
        #pragma unroll
        for (int ni = 0; ni < 4; ++ni)
            acc[mi][ni] = __builtin_amdgcn_mfma_f32_16x16x32_bf16(
                af[mi], bfr[ni], acc[mi][ni], 0, 0, 0);
    __builtin_amdgcn_s_setprio(0);
}

__device__ __forceinline__ void chunk_mfma_a0(const __bf16* __restrict__ act0,
    const __bf16* __restrict__ buf, int c, int rA, int q, int wncol,
    f32x4 (&acc)[4][4]) {
    const int g   = c * 4 + q;                  // 0..7
    const int sla = (g ^ (rA & 7)) << 3;
    bf16x8 af[4], bfr[4];
    #pragma unroll
    for (int mi = 0; mi < 4; ++mi)
        af[mi] = *(const bf16x8*)&act0[(mi * 16 + rA) * 64 + sla];
    #pragma unroll
    for (int ni = 0; ni < 4; ++ni) {
        int wr = wncol + ni * 16 + rA;
        bfr[ni] = *(const bf16x8*)&buf[wr * 32 + ((q ^ ((wr >> 1) & 3)) << 3)];
    }
    __builtin_amdgcn_s_setprio(1);
    #pragma unroll
    for (int mi = 0; mi < 4; ++mi)
        #pragma unroll
        for (int ni = 0; ni < 4; ++ni)
            acc[mi][ni] = __builtin_amdgcn_mfma_f32_16x16x32_bf16(
                af[mi], bfr[ni], acc[mi][ni], 0, 0, 0);
    __builtin_amdgcn_s_setprio(0);
}

// proj chunk: K=64, W buf [256][64], two sub-k of 8 MFMAs
__device__ __forceinline__ void chunk_mfma_proj(const __bf16* __restrict__ sAct,
    const __bf16* __restrict__ buf, int c, int rA, int q, int wnp,
    f32x4 (&accp)[4][2]) {
    __builtin_amdgcn_s_setprio(1);
    #pragma unroll
    for (int s = 0; s < 2; ++s) {
        const int g   = c * 8 + s * 4 + q;
        const int sla = ((g & 56) | ((g & 7) ^ (rA & 7))) << 3;
        bf16x8 af[4], bfr[2];
        #pragma unroll
        for (int mi = 0; mi < 4; ++mi)
            af[mi] = *(const bf16x8*)&sAct[(mi * 16 + rA) * 512 + sla];
        #pragma unroll
        for (int ni = 0; ni < 2; ++ni) {
            int wr = wnp + ni * 16 + rA;
            int gB = s * 4 + q;
            bfr[ni] = *(const bf16x8*)&buf[wr * 64 + ((gB ^ (wr & 7)) << 3)];
        }
        #pragma unroll
        for (int mi = 0; mi < 4; ++mi)
            #pragma unroll
            for (int ni = 0; ni < 2; ++ni)
                accp[mi][ni] = __builtin_amdgcn_mfma_f32_16x16x32_bf16(
                    af[mi], bfr[ni], accp[mi][ni], 0, 0, 0);
    }
    __builtin_amdgcn_s_setprio(0);
}

template <int ACTn>   // 1 = lrelu(0.1), 2 = relu
__device__ __forceinline__ void writeback_act(__bf16* __restrict__ sAct,
    f32x4 (&acc)[4][4], const float* __restrict__ bv,
    int wn, int ccol, int crow) {
    #pragma unroll
    for (int mi = 0; mi < 4; ++mi)
        #pragma unroll
        for (int ni = 0; ni < 4; ++ni) {
            int cc = wn + ni * 16 + ccol;
            int g  = cc >> 3;
            #pragma unroll
            for (int p = 0; p < 4; ++p) {
                int rr = mi * 16 + crow + p;
                float v = acc[mi][ni][p] + bv[ni];
                if (ACTn == 1) v = (v > 0.0f) ? v : 0.1f * v;
                else           v = fmaxf(v, 0.0f);
                int sl = (g & 56) | ((g & 7) ^ (rr & 7));
                sAct[rr * 512 + sl * 8 + (cc & 7)] = (__bf16)v;
            }
        }
}

// one 512-wide layer, 3-slot ring, base slot B3 = (layer's global chunk base)%3.
// position c: {vmcnt(4); BAR; stage chunk c+2 -> slot (B3+c+2)%3; MFMA c}.
// c=14/15 stage next layer's chunk 0/1. Boundary: {BAR; writeback; lgkm0; BAR}.
template <int ACTn, int B3>
__device__ __forceinline__ void layer512_pipe3(
    __bf16* __restrict__ sAct, __bf16* __restrict__ sbase,
    const __bf16* __restrict__ W,
    const __bf16* __restrict__ Wn, int Kn, bool n512, int k0n_c0, int k0n_c1,
    const float* __restrict__ bv,
    int wn, int rA, int q, int ccol, int crow, int wid, int lane) {
    f32x4 acc[4][4];
    #pragma unroll
    for (int i = 0; i < 4; ++i)
        #pragma unroll
        for (int j = 0; j < 4; ++j) acc[i][j] = (f32x4)0.0f;
    #pragma unroll
    for (int c = 0; c < 16; ++c) {
        P_WAITN(4); P_BAR;
        __bf16* dst = sbase + (((B3 + c + 2) % 3) * SLOT_ELEMS);
        if (c <= 13)      stage_chunk(W, 512, (c + 2) * 32, true, dst, wid, lane);
        else if (c == 14) stage_chunk(Wn, Kn, k0n_c0, n512, dst, wid, lane);
        else              stage_chunk(Wn, Kn, k0n_c1, n512, dst, wid, lane);
        chunk_mfma4(sAct, sbase + (((B3 + c) % 3) * SLOT_ELEMS), c, rA, q, wn, acc);
    }
    P_BAR;                       // all waves' sAct reads retired
    writeback_act<ACTn>(sAct, acc, bv, wn, ccol, crow);
    P_LGKM0; P_BAR;              // writes visible; in-flight stages untouched
}

__global__ __launch_bounds__(512) void mlp_fused(
    const __bf16* __restrict__ a0,   // agg0b [N_PAD][64]
    const __bf16* __restrict__ w1, const float* __restrict__ b1,
    const __bf16* __restrict__ w2, const float* __restrict__ b2,
    const __bf16* __restrict__ w3, const float* __restrict__ b3,
    const __bf16* __restrict__ w4, const float* __restrict__ b4,
    const __bf16* __restrict__ wp,   // wml [256][512]
    __bf16* __restrict__ tg)         // t [N_PAD][256]
{
    __shared__ __bf16 lds[81920];    // 160 KB exactly
    __bf16* sAct  = lds;             // [64][512]; first 8 KB doubles as act0 [64][64]
    __bf16* sbase = lds + 32768;     // 3 ring slots x 32 KB

    const int tid  = threadIdx.x;
    const int wid  = tid >> 6;
    const int lane = tid & 63;
    const long blockRow = (long)blockIdx.x * 64;

    const int rA   = lane & 15;
    const int q    = lane >> 4;
    const int ccol = lane & 15;
    const int crow = (lane >> 4) << 2;
    const int wn   = wid << 6;       // 512-wide layers
    const int wnp  = wid << 5;       // proj (256-wide)

    // bias preload (VMEM kept out of the counted pipeline; drained at g0's vmcnt(0))
    float bv1[4], bv2[4], bv3[4], bv4[4];
    #pragma unroll
    for (int ni = 0; ni < 4; ++ni) {
        int idx = wn + ni * 16 + ccol;
        bv1[ni] = b1[idx]; bv2[ni] = b2[idx]; bv3[ni] = b3[idx]; bv4[ni] = b4[idx];
    }

    // prime: act0 (1 gl/wave, overlaid at lds base) + g0 (slot0) + g1 (slot1)
    {
        int srow = lane >> 3;
        int skg  = (lane & 7) ^ srow;
        gl_lds16(a0 + (blockRow + wid * 8 + srow) * 64 + skg * 8, lds + wid * 512);
    }
    stage_chunk(w1, 64, 0,  true, sbase,              wid, lane);  // g0 -> slot0
    stage_chunk(w1, 64, 32, true, sbase + SLOT_ELEMS, wid, lane);  // g1 -> slot1

    // ---- L1: 64 -> 512 (A = act0), B3 = 0 ----
    {
        f32x4 acc[4][4];
        #pragma unroll
        for (int i = 0; i < 4; ++i)
            #pragma unroll
            for (int j = 0; j < 4; ++j) acc[i][j] = (f32x4)0.0f;
        // g0: full drain (prime issue order not provably counted)
        P_WAIT0; P_BAR;
        stage_chunk(w2, 512, 0, true, sbase + 2 * SLOT_ELEMS, wid, lane);  // g2 -> slot2
        chunk_mfma_a0(lds, sbase, 0, rA, q, wn, acc);
        // g1: data already drained; vmcnt(4) no-op but keeps pattern uniform
        P_WAITN(4); P_BAR;
        stage_chunk(w2, 512, 32, true, sbase, wid, lane);                  // g3 -> slot0
        chunk_mfma_a0(lds, sbase + SLOT_ELEMS, 1, rA, q, wn, acc);
        P_BAR;                                   // all act0 reads retired
        writeback_act<1>(sAct, acc, bv1, wn, ccol, crow);   // overwrites act0 region
        P_LGKM0; P_BAR;
    }

    // ---- L2 (B3=2), L3 (B3=0), L4 (B3=1, +b4 relu) ----
    layer512_pipe3<1, 2>(sAct, sbase, w2, w3, 512, true, 0, 32, bv2,
                         wn, rA, q, ccol, crow, wid, lane);
    layer512_pipe3<1, 0>(sAct, sbase, w3, w4, 512, true, 0, 32, bv3,
                         wn, rA, q, ccol, crow, wid, lane);
    layer512_pipe3<2, 1>(sAct, sbase, w4, wp, 512, false, 0, 64, bv4,
                         wn, rA, q, ccol, crow, wid, lane);

    // ---- proj: 512 -> 256 (8 chunks of K=64), B3 = 2, no bias/act ----
    {
        f32x4 accp[4][2];
        #pragma unroll
        for (int i = 0; i < 4; ++i)
            #pragma unroll
            for (int j = 0; j < 2; ++j) accp[i][j] = (f32x4)0.0f;
        #pragma unroll
        for (int c = 0; c < 8; ++c) {
            // ledger: c<=6 have 8 in flight -> vmcnt(4); c==7 has only its own 4
            if (c == 7) { P_WAIT0; } else { P_WAITN(4); }
            P_BAR;
            if (c <= 5)
                stage_chunk(wp, 512, (c + 2) * 64, false,
                            sbase + (((4 + c) % 3) * SLOT_ELEMS), wid, lane);
            chunk_mfma_proj(sAct, sbase + (((2 + c) % 3) * SLOT_ELEMS),
                            c, rA, q, wnp, accp);
        }
        P_BAR;   // all slot reads retired (slot0's last reader was c=7)
        // stage 64x256 bf16 t-tile into slot0 region, then coalesced 16B stores
        __bf16* s0 = sbase;
        #pragma unroll
        for (int mi = 0; mi < 4; ++mi)
            #pragma unroll
            for (int ni = 0; ni < 2; ++ni)
                #pragma unroll
                for (int p = 0; p < 4; ++p)
                    s0[(mi * 16 + crow + p) * 256 + wnp + ni * 16 + ccol] =
                        (__bf16)accp[mi][ni][p];
        __syncthreads();
        int rr = tid >> 3;
        int c0 = (tid & 7) << 5;
        const bf16x8* s = (const bf16x8*)&s0[rr * 256 + c0];
        __bf16* d = tg + (blockRow + rr) * 256 + c0;
        #pragma unroll
        for (int i = 0; i < 4; ++i) *(bf16x8*)(d + i * 8) = s[i];
    }
}

// ---------------- 128x128 MFMA GEMM core (heads only now) ----------------------
template <int NCOL>
__device__ __forceinline__ void swizzle_xy(int bid, int& x, int& y) {
    int grp  = bid / (8 * NCOL);
    int rem  = bid - grp * (8 * NCOL);
    int base = grp * 8;
    int width = MT - base; if (width > 8) width = 8;
    x = base + rem % width;
    y = rem / width;
}

template <int ACT, bool BIAS, bool OUT_BF16, bool MCHK>
__device__ __forceinline__ void gemm_core(
    const __bf16* __restrict__ A, int lda, const __bf16* __restrict__ W,
    const float* __restrict__ bias, void* __restrict__ Cout, int ldc,
    int K, long Mstore, long blockRow, int blockCol,
    __bf16* __restrict__ smem) {
    __bf16* As = smem;
    __bf16* Ws = smem + 8192;
    const int tid  = threadIdx.x;
    const int wid  = tid >> 6;
    const int lane = tid & 63;
    const int wm = (wid >> 1) << 6;
    const int wn = (wid & 1) << 6;

    f32x4 acc[4][4];
    #pragma unroll
    for (int i = 0; i < 4; ++i)
        #pragma unroll
        for (int j = 0; j < 4; ++j) acc[i][j] = (f32x4)0.0f;

    const int srow = lane >> 3;
    const int skg  = (lane & 7) ^ srow;
    const __bf16* gA[4]; const __bf16* gW[4];
    __bf16 *lA[4], *lW[4];
    #pragma unroll
    for (int i = 0; i < 4; ++i) {
        int c = wid * 4 + i;
        gA[i] = A + (blockRow + c * 8 + srow) * (long)lda + skg * 8;
        gW[i] = W + ((long)blockCol + c * 8 + srow) * (long)K + skg * 8;
        lA[i] = As + c * 512;
        lW[i] = Ws + c * 512;
    }

    const int rA = lane & 15;
    const int q  = lane >> 4;
    const int r7 = rA & 7;

    for (int k0 = 0; k0 < K; k0 += 64) {
        #pragma unroll
        for (int i = 0; i < 4; ++i) gl_lds16(gA[i] + k0, lA[i]);
        #pragma unroll
        for (int i = 0; i < 4; ++i) gl_lds16(gW[i] + k0, lW[i]);
        __syncthreads();

        #pragma unroll
        for (int s = 0; s < 2; ++s) {
            const int slot = ((s * 4 + q) ^ r7) * 8;
            bf16x8 af[4], bf[4];
            #pragma unroll
            for (int mi = 0; mi < 4; ++mi)
                af[mi] = *(const bf16x8*)&As[(wm + mi * 16 + rA) * 64 + slot];
            #pragma unroll
            for (int ni = 0; ni < 4; ++ni)
                bf[ni] = *(const bf16x8*)&Ws[(wn + ni * 16 + rA) * 64 + slot];
            #pragma unroll
            for (int mi = 0; mi < 4; ++mi)
                #pragma unroll
                for (int ni = 0; ni < 4; ++ni)
                    acc[mi][ni] = __builtin_amdgcn_mfma_f32_16x16x32_bf16(
                        af[mi], bf[ni], acc[mi][ni], 0, 0, 0);
        }
        __syncthreads();
    }

    const int ccol = lane & 15;
    const int crow = (lane >> 4) << 2;
    if (OUT_BF16 && !MCHK) {
        #pragma unroll
        for (int mi = 0; mi < 4; ++mi) {
            #pragma unroll
            for (int ni = 0; ni < 4; ++ni) {
                int gc = wn + ni * 16 + ccol;
                float bv = BIAS ? bias[blockCol + gc] : 0.0f;
                #pragma unroll
                for (int r = 0; r < 4; ++r) {
                    float v = acc[mi][ni][r] + bv;
                    if (ACT == 1) v = (v > 0.0f) ? v : 0.1f * v;
                    else if (ACT == 2) v = fmaxf(v, 0.0f);
                    smem[(wm + mi * 16 + crow + r) * 128 + gc] = (__bf16)v;
                }
            }
        }
        __syncthreads();
        #pragma unroll
        for (int i = 0; i < 8; ++i) {
            int o   = (i * 256 + tid) * 8;
            int row = o >> 7;
            int co  = o & 127;
            *(bf16x8*)((__bf16*)Cout + (blockRow + row) * (long)ldc + blockCol + co) =
                *(const bf16x8*)&smem[o];
        }
    } else if (!OUT_BF16) {
        // fp32 staged path (ldc == 128): two 64-row halves in the dead 32 KB LDS,
        // coalesced f32x4 stores, row-guarded.
        float* fsmem = (float*)smem;
        #pragma unroll
        for (int half = 0; half < 2; ++half) {
            __syncthreads();
            if ((wm >> 6) == half) {
                #pragma unroll
                for (int mi = 0; mi < 4; ++mi) {
                    #pragma unroll
                    for (int ni = 0; ni < 4; ++ni) {
                        int gc = wn + ni * 16 + ccol;
                        float bv = BIAS ? bias[blockCol + gc] : 0.0f;
                        #pragma unroll
                        for (int r = 0; r < 4; ++r) {
                            float v = acc[mi][ni][r] + bv;
                            if (ACT == 1) v = (v > 0.0f) ? v : 0.1f * v;
                            else if (ACT == 2) v = fmaxf(v, 0.0f);
                            fsmem[(mi * 16 + crow + r) * 128 + gc] = v;
                        }
                    }
                }
            }
            __syncthreads();
            #pragma unroll
            for (int i = 0; i < 8; ++i) {
                int o   = i * 256 + tid;
                int row = o >> 5;
                int co  = (o & 31) * 4;
                long gr = blockRow + half * 64 + row;
                if (!MCHK || gr < Mstore)
                    *(f32x4*)((float*)Cout + gr * (long)ldc + blockCol + co) =
                        *(const f32x4*)&fsmem[o * 4];
            }
        }
    } else {
        #pragma unroll
        for (int mi = 0; mi < 4; ++mi) {
            #pragma unroll
            for (int ni = 0; ni < 4; ++ni) {
                long gr0 = blockRow + wm + mi * 16 + crow;
                int  gc  = blockCol + wn + ni * 16 + ccol;
                float bv = BIAS ? bias[gc] : 0.0f;
                #pragma unroll
                for (int r = 0; r < 4; ++r) {
                    long gr = gr0 + r;
                    if (!MCHK || gr < Mstore) {
                        float v = acc[mi][ni][r] + bv;
                        if (ACT == 1) v = (v > 0.0f) ? v : 0.1f * v;
                        else if (ACT == 2) v = fmaxf(v, 0.0f);
                        ((__bf16*)Cout)[gr * ldc + gc] = (__bf16)v;
                    }
                }
            }
        }
    }
}

// both heads in one 1D dispatch; K=128 (each head uses its half of p), lda=256.
__global__ __launch_bounds__(256) void gemm_heads(
    const __bf16* __restrict__ p, const __bf16* __restrict__ wm2,
    const float* __restrict__ b_m2, float* __restrict__ mu,
    const __bf16* __restrict__ wl2, const float* __restrict__ b_l2,
    float* __restrict__ lv) {
    __shared__ __bf16 smem[128 * 128];
    int x, hd;
    swizzle_xy<2>(blockIdx.x, x, hd);
    if (hd == 0)
        gemm_core<0, true, false, true>(p, 256, wm2, b_m2, mu, 128, 128, N_NODES,
                                        (long)x * 128, 0, smem);
    else
        gemm_core<0, true, false, true>(p + 128, 256, wl2, b_l2, lv, 128, 128, N_NODES,
                                        (long)x * 128, 0, smem);
}

extern "C" void kernel_launch(void* const* d_in, const int* in_sizes, int n_in,
                              void* d_out, int out_size, void* d_ws, size_t ws_size,
                              hipStream_t stream) {
    const float* x    = (const float*)d_in[0];
    const int*   ei   = (const int*)d_in[1];
    const float* W_s1 = (const float*)d_in[2];
    const float* b_s1 = (const float*)d_in[3];
    const float* W_s2 = (const float*)d_in[4];
    const float* b_s2 = (const float*)d_in[5];
    const float* W_s3 = (const float*)d_in[6];
    const float* b_s3 = (const float*)d_in[7];
    const float* W_s4 = (const float*)d_in[8];
    const float* b_s4 = (const float*)d_in[9];
    const float* W_m1 = (const float*)d_in[10];
    const float* b_m1 = (const float*)d_in[11];
    const float* W_m2 = (const float*)d_in[12];
    const float* b_m2 = (const float*)d_in[13];
    const float* W_l1 = (const float*)d_in[14];
    const float* b_l1 = (const float*)d_in[15];
    const float* W_l2 = (const float*)d_in[16];
    const float* b_l2 = (const float*)d_in[17];

    char* ws = (char*)d_ws;
    size_t off = 0;
    auto carve = [&](size_t bytes) -> void* {
        void* p = ws + off;
        off = (off + bytes + 255) & ~(size_t)255;
        return p;
    };
    int* ptr  = (int*)carve((size_t)(N_NODES + 1) * 4);
    int* col  = (int*)carve((size_t)E_EDGES * 4);
    int* bsum = (int*)carve(SCAN_B * 4);
    int* boff = (int*)carve(SCAN_B * 4);
    __bf16* wbuf = (__bf16*)carve((size_t)WTOT * 2);
    __bf16* w1  = wbuf;
    __bf16* w2  = wbuf +  32768;
    __bf16* w3  = wbuf + 294912;
    __bf16* w4  = wbuf + 557056;
    __bf16* wml = wbuf + 819200;   // [W_m1 ; W_l1] rows, 256x512
    __bf16* wm2 = wbuf + 950272;
    __bf16* wl2 = wbuf + 966656;
    __bf16* xb    = (__bf16*)carve((size_t)XN * 2);
    __bf16* agg0b = (__bf16*)carve((size_t)N_PAD * 64 * 2);
    __bf16* B1    = (__bf16*)carve((size_t)N_PAD * 512 * 2);
    __bf16* B2    = (__bf16*)carve((size_t)N_PAD * 512 * 2);

    // count/cursor arrays alias B1/B2 — first real writes happen after CSR build
    // completes (stream-ordered).
    int* cnt = (int*)B1;
    int* cur = (int*)B2;

    (void)hipMemsetAsync(cnt, 0, (size_t)N_NODES * 4, stream);
    (void)hipMemsetAsync(cur, 0, (size_t)N_NODES * 4, stream);

    // CSR build
    const int NB = (N_NODES + SCAN_B - 1) / SCAN_B;  // 49
    count_deg<<<E_EDGES / 256, 256, 0, stream>>>(ei, cnt);
    scan_block<<<NB, SCAN_B, 0, stream>>>(cnt, ptr, bsum, N_NODES);
    scan_bsums<<<1, SCAN_B, 0, stream>>>(bsum, boff, NB, &ptr[N_NODES]);
    scan_add<<<NB, SCAN_B, 0, stream>>>(ptr, boff, N_NODES);
    fill_csr<<<E_EDGES / 256, 256, 0, stream>>>(ei, ptr, cur, col);

    // one-shot conversions
    cvt_all<<<(XN + WTOT + 255) / 256, 256, 0, stream>>>(
        x, W_s1, W_s2, W_s3, W_s4, W_m1, W_l1, W_m2, W_l2, xb, wbuf);

    // first aggregation
    agg0_gather<<<N_PAD / 4, 256, 0, stream>>>(xb, ptr, col, agg0b);

    // fused shared-MLP + projection: agg0b -> t (N_PAD x 256 bf16)
    __bf16* t = B1;
    mlp_fused<<<N_PAD / 64, 512, 0, stream>>>(agg0b, w1, b_s1, w2, b_s2,
                                              w3, b_s3, w4, b_s4, wml, t);

    // second aggregation, fused bias+relu
    __bf16* p = B2;  // N x 256 bf16
    aggt_gather<<<(N_NODES + 7) / 8, 256, 0, stream>>>(t, ptr, col, b_m1, b_l1, p);

    // heads (one swizzled 1D dispatch)
    float* mu = (float*)d_out;
    float* lv = mu + (size_t)N_NODES * 128;
    gemm_heads<<<MT * 2, 256, 0, stream>>>(p, wm2, b_m2, mu, wl2, b_l2, lv);
}